// Round 15
// baseline (397.923 us; speedup 1.0000x reference)
//
#include <hip/hip_runtime.h>
#include <hip/hip_bf16.h>
#include <math.h>

#define B_ 256
#define N_ 576
#define F_ 384
#define D_ 256
#define K_ 8

// output offsets (floats)
#define OFF_PART   0
#define OFF_ASSIGN 524288
#define OFF_SAL    1703936
#define OFF_FEAT   1705984
#define OFF_GATE   39454720

// workspace layout (floats)
#define WS_STATS   0
#define WS_MACC    65536
#define WS_MASS    589824
#define WS_PROTON  591872
#define WS_INVN    1116160
#define WS_BTW     1263616

using s16x8 = __attribute__((ext_vector_type(8))) short;
using f32x4 = __attribute__((ext_vector_type(4))) float;

__device__ __forceinline__ float gelu_exact(float x) {
    return 0.5f * x * (1.0f + erff(x * 0.70710678118654752f));
}

__device__ __forceinline__ unsigned short f2b(float f) {
    __hip_bfloat16 h = __float2bfloat16(f);
    unsigned short u;
    __builtin_memcpy(&u, &h, 2);
    return u;
}

__global__ void k0_zero(float* __restrict__ p, int n) {
    int i = blockIdx.x * blockDim.x + threadIdx.x;
    if (i < n) p[i] = 0.f;
}

// one-off: Bt[n][k] = bf16(w_proj[k][n])
__global__ void kB_conv(const float* __restrict__ w, unsigned short* __restrict__ bt) {
    int k = threadIdx.x;   // 384
    int n = blockIdx.x;    // 256
    bt[n * 384 + k] = f2b(w[k * 256 + n]);
}

// K1: r13's verified math at BK=32 with ~25.6 KB LDS -> 4-6 blocks/CU
// (occupancy probe: latency-serialization theory). 12 chunks, 1 K-step each,
// reg-prefetch staging, swapped MFMA operands:
// acc[m][n][r] = C[row = m*16 + l15][col = w*64 + n*16 + l4*4 + r].
__global__ __launch_bounds__(256, 4) void k1_occ(
    const float* __restrict__ patch, const unsigned short* __restrict__ btw,
    const float* __restrict__ bias, const float* __restrict__ g,
    const float* __restrict__ bb, float* __restrict__ feat,
    float* __restrict__ stats, float* __restrict__ invn)
{
    __shared__ __align__(16) unsigned short As[64 * 36];    //  4.6 KB (pad 72B: 2-way free)
    __shared__ __align__(16) unsigned short Bs[256 * 36];   // 18.4 KB
    __shared__ float rsum[4][64];
    __shared__ float rsq[4][64];
    __shared__ float muS[64], rsS[64];

    const int t = threadIdx.x;
    const int w = t >> 6;
    const int lane = t & 63;
    const int l15 = lane & 15;
    const int l4 = lane >> 4;
    const size_t rowbase = (size_t)blockIdx.x * 64;
    const int bidx = blockIdx.x / 9;   // 9 blocks per batch (9*64 = 576)

    f32x4 acc[4][4];
#pragma unroll
    for (int m = 0; m < 4; ++m)
#pragma unroll
        for (int n = 0; n < 4; ++n)
            acc[m][n] = (f32x4){0.f, 0.f, 0.f, 0.f};

    const int ar = t >> 2;          // A-stage row 0..63
    const int ak = (t & 3) * 8;     // A-stage k offset (8 f32 per thread)
    const float* aptr = patch + (rowbase + ar) * F_ + ak;
    const unsigned short* bptr = btw + (size_t)t * F_;   // thread t stages col t

    float4 pa0, pa1;
    s16x8 pb[4];

    // prologue: load chunk 0 into registers
    pa0 = *(const float4*)(aptr);
    pa1 = *(const float4*)(aptr + 4);
#pragma unroll
    for (int p = 0; p < 4; ++p) pb[p] = *(const s16x8*)(bptr + p * 8);

    for (int c = 0; c < 12; ++c) {
        __syncthreads();   // previous compute done reading LDS
        {
            s16x8 ca;
            ca[0] = (short)f2b(pa0.x); ca[1] = (short)f2b(pa0.y);
            ca[2] = (short)f2b(pa0.z); ca[3] = (short)f2b(pa0.w);
            ca[4] = (short)f2b(pa1.x); ca[5] = (short)f2b(pa1.y);
            ca[6] = (short)f2b(pa1.z); ca[7] = (short)f2b(pa1.w);
            *(s16x8*)&As[ar * 36 + ak] = ca;
#pragma unroll
            for (int p = 0; p < 4; ++p)
                *(s16x8*)&Bs[t * 36 + p * 8] = pb[p];
        }
        __syncthreads();
        if (c < 11) {
            const int k1 = (c + 1) * 32;
            pa0 = *(const float4*)(aptr + k1);
            pa1 = *(const float4*)(aptr + k1 + 4);
#pragma unroll
            for (int p = 0; p < 4; ++p) pb[p] = *(const s16x8*)(bptr + k1 + p * 8);
        }
        {
            s16x8 afr[4], bfr[4];
#pragma unroll
            for (int m = 0; m < 4; ++m)
                afr[m] = *(const s16x8*)&As[(m * 16 + l15) * 36 + l4 * 8];
#pragma unroll
            for (int n = 0; n < 4; ++n)
                bfr[n] = *(const s16x8*)&Bs[(w * 64 + n * 16 + l15) * 36 + l4 * 8];
#pragma unroll
            for (int m = 0; m < 4; ++m)
#pragma unroll
                for (int n = 0; n < 4; ++n)
                    acc[m][n] = __builtin_amdgcn_mfma_f32_16x16x32_bf16(bfr[n], afr[m], acc[m][n], 0, 0, 0);
        }
    }

    // ---- r13's verified swapped-layout epilogue ----
    float4 bias4[4], g4[4], bb4[4];
#pragma unroll
    for (int n = 0; n < 4; ++n) {
        const int cb = w * 64 + n * 16 + l4 * 4;
        bias4[n] = *(const float4*)&bias[cb];
        g4[n]    = *(const float4*)&g[cb];
        bb4[n]   = *(const float4*)&bb[cb];
    }
#pragma unroll
    for (int m = 0; m < 4; ++m)
#pragma unroll
        for (int n = 0; n < 4; ++n) {
            acc[m][n][0] += bias4[n].x;
            acc[m][n][1] += bias4[n].y;
            acc[m][n][2] += bias4[n].z;
            acc[m][n][3] += bias4[n].w;
        }

    float ps[4], pq[4];
#pragma unroll
    for (int m = 0; m < 4; ++m) {
        float s = 0.f, s2 = 0.f;
#pragma unroll
        for (int n = 0; n < 4; ++n)
#pragma unroll
            for (int r = 0; r < 4; ++r) {
                float x = acc[m][n][r];
                s += x; s2 += x * x;
            }
        s += __shfl_xor(s, 16);  s += __shfl_xor(s, 32);
        s2 += __shfl_xor(s2, 16); s2 += __shfl_xor(s2, 32);
        ps[m] = s; pq[m] = s2;
    }
    if (l4 == 0) {
#pragma unroll
        for (int m = 0; m < 4; ++m) {
            rsum[w][m * 16 + l15] = ps[m];
            rsq[w][m * 16 + l15] = pq[m];
        }
    }
    __syncthreads();
    if (t < 64) {
        float s = rsum[0][t] + rsum[1][t] + rsum[2][t] + rsum[3][t];
        float q = rsq[0][t] + rsq[1][t] + rsq[2][t] + rsq[3][t];
        float mean = s * (1.f / 256.f);
        float var = q * (1.f / 256.f) - mean * mean;
        muS[t] = mean;
        rsS[t] = rsqrtf(var + 1e-5f);
    }
    __syncthreads();

    float cst[4][4];
#pragma unroll
    for (int n = 0; n < 4; ++n)
#pragma unroll
        for (int r = 0; r < 4; ++r) cst[n][r] = 0.f;

#pragma unroll
    for (int m = 0; m < 4; ++m) {
        const int row = m * 16 + l15;
        const float mu = muS[row], ri = rsS[row];
        float qs = 0.f;
        float* fp = feat + (rowbase + row) * 256 + w * 64 + l4 * 4;
#pragma unroll
        for (int n = 0; n < 4; ++n) {
            float z0 = gelu_exact((acc[m][n][0] - mu) * ri * g4[n].x + bb4[n].x);
            float z1 = gelu_exact((acc[m][n][1] - mu) * ri * g4[n].y + bb4[n].y);
            float z2 = gelu_exact((acc[m][n][2] - mu) * ri * g4[n].z + bb4[n].z);
            float z3 = gelu_exact((acc[m][n][3] - mu) * ri * g4[n].w + bb4[n].w);
            float4 zv = {z0, z1, z2, z3};
            *(float4*)(fp + n * 16) = zv;
            cst[n][0] += z0; cst[n][1] += z1; cst[n][2] += z2; cst[n][3] += z3;
            qs += z0 * z0 + z1 * z1 + z2 * z2 + z3 * z3;
        }
        qs += __shfl_xor(qs, 16); qs += __shfl_xor(qs, 32);
        if (l4 == 0) rsq[w][row] = qs;   // reuse rsq: z^2 staging (safe after barrier above)
    }
#pragma unroll
    for (int n = 0; n < 4; ++n)
#pragma unroll
        for (int r = 0; r < 4; ++r) {
            float cv = cst[n][r];
            cv += __shfl_xor(cv, 1); cv += __shfl_xor(cv, 2);
            cv += __shfl_xor(cv, 4); cv += __shfl_xor(cv, 8);
            if (l15 == 0)
                atomicAdd(&stats[bidx * 256 + w * 64 + n * 16 + l4 * 4 + r], cv);
        }
    __syncthreads();
    if (t < 64) {
        float tot = rsq[0][t] + rsq[1][t] + rsq[2][t] + rsq[3][t];
        invn[rowbase + t] = 1.f / fmaxf(sqrtf(tot), 1e-12f);
    }
}

// K3: router + blended-normalized prototypes. grid 256.
__global__ __launch_bounds__(256) void k3_router(
    const float* __restrict__ stats, const int* __restrict__ alt_idx,
    const int* __restrict__ epoch_p,
    const float* __restrict__ r_alt_emb, const float* __restrict__ r_wf,
    const float* __restrict__ r_bf, const float* __restrict__ r_w1,
    const float* __restrict__ r_b1, const float* __restrict__ r_w2,
    const float* __restrict__ r_b2, const float* __restrict__ protos,
    float* __restrict__ gate_out, float* __restrict__ proto_n)
{
    __shared__ float fs[256];
    __shared__ float cv[128];
    __shared__ float hb[64];
    __shared__ float lg[4];
    __shared__ float gate[4];
    __shared__ float pl[8 * 260];
    __shared__ float nrm[8];
    const int t = threadIdx.x, b = blockIdx.x;
    fs[t] = stats[b * D_ + t] * (1.f / (float)N_);
    __syncthreads();
    if (t < 64) {
        float a = 0.f;
        for (int d = 0; d < 256; ++d) a += fs[d] * r_wf[d * 64 + t];
        cv[t] = fmaxf(a + r_bf[t], 0.f);
    } else if (t < 128) {
        int alt = alt_idx[b];
        cv[t] = r_alt_emb[alt * 64 + (t - 64)];
    }
    __syncthreads();
    if (t < 64) {
        float a = 0.f;
        for (int d = 0; d < 128; ++d) a += cv[d] * r_w1[d * 64 + t];
        hb[t] = fmaxf(a + r_b1[t], 0.f);
    }
    __syncthreads();
    if (t < 4) {
        float a = 0.f;
        for (int d = 0; d < 64; ++d) a += hb[d] * r_w2[d * 4 + t];
        int ep = epoch_p[0];
        float warm = fminf((float)ep * (1.f / 8.f), 1.f);
        float temp = 2.f * (1.f - warm) + 0.5f * warm;
        lg[t] = (a + r_b2[t]) / temp;
    }
    __syncthreads();
    if (t == 0) {
        float m = fmaxf(fmaxf(lg[0], lg[1]), fmaxf(lg[2], lg[3]));
        float e0 = expf(lg[0] - m), e1 = expf(lg[1] - m);
        float e2 = expf(lg[2] - m), e3 = expf(lg[3] - m);
        float s = e0 + e1 + e2 + e3;
        gate[0] = e0 / s; gate[1] = e1 / s; gate[2] = e2 / s; gate[3] = e3 / s;
    }
    __syncthreads();
    if (t < 4) gate_out[b * 4 + t] = gate[t];
    float g0 = gate[0], g1 = gate[1], g2 = gate[2], g3 = gate[3];
#pragma unroll
    for (int k = 0; k < 8; ++k) {
        float p = g0 * protos[(0 * 8 + k) * 256 + t] + g1 * protos[(1 * 8 + k) * 256 + t]
                + g2 * protos[(2 * 8 + k) * 256 + t] + g3 * protos[(3 * 8 + k) * 256 + t];
        pl[k * 260 + t] = p;
    }
    __syncthreads();
    const int wave = t >> 6, lane = t & 63;
#pragma unroll
    for (int kk = 0; kk < 2; ++kk) {
        int k = wave * 2 + kk;
        float4 v = *(const float4*)(&pl[k * 260 + lane * 4]);
        float s2 = v.x * v.x + v.y * v.y + v.z * v.z + v.w * v.w;
#pragma unroll
        for (int m = 1; m < 64; m <<= 1) s2 += __shfl_xor(s2, m);
        if (lane == 0) nrm[k] = 1.f / fmaxf(sqrtf(s2), 1e-12f);
    }
    __syncthreads();
#pragma unroll
    for (int k = 0; k < 8; ++k)
        proto_n[((size_t)(b * 8 + k)) * 256 + t] = pl[k * 260 + t] * nrm[k];
}

// K4: sim uses precomputed invn. grid (4,256), 9 tiles each.
__global__ __launch_bounds__(256) void k4_part(
    const float* __restrict__ feat, const float* __restrict__ proto_n,
    const float* __restrict__ invn,
    float* __restrict__ assign_out, float* __restrict__ macc_ws,
    float* __restrict__ mass_ws)
{
    __shared__ float pp[8 * 260];
    __shared__ float ft[16 * 260];
    __shared__ float asg[16 * 8];
    __shared__ float inrm[16];
    const int t = threadIdx.x, b = blockIdx.y;
#pragma unroll
    for (int k = 0; k < 8; ++k) pp[k * 260 + t] = proto_n[((size_t)(b * 8 + k)) * 256 + t];
    float macc[8];
#pragma unroll
    for (int k = 0; k < 8; ++k) macc[k] = 0.f;
    float massr = 0.f;
    const int sn = t >> 4;
    const int sk = (t >> 1) & 7;
    const int hf = t & 1;
    const int lc = (t & 15) * 4;
    const int t0 = blockIdx.x * 9;
    for (int tile = t0; tile < t0 + 9; ++tile) {
        int n0 = tile * 16;
        __syncthreads();
        const float* fsrc = feat + ((size_t)(b * N_ + n0 + sn) * D_) + lc;
#pragma unroll
        for (int i = 0; i < 4; ++i) {
            float4 v = *(const float4*)(fsrc + 64 * i);
            *(float4*)(&ft[sn * 260 + lc + 64 * i]) = v;
        }
        if (t < 16) inrm[t] = invn[(size_t)b * N_ + n0 + t];
        __syncthreads();
        {
            const float4* fp = (const float4*)(&ft[sn * 260 + hf * 128]);
            const float4* qp = (const float4*)(&pp[sk * 260 + hf * 128]);
            float a = 0.f;
#pragma unroll 8
            for (int dd = 0; dd < 32; ++dd) {
                float4 fv = fp[dd], qv = qp[dd];
                a += fv.x * qv.x + fv.y * qv.y + fv.z * qv.z + fv.w * qv.w;
            }
            a += __shfl_xor(a, 1);
            float sim = a * inrm[sn] * (1.f / 0.07f);
            float m = sim;
            m = fmaxf(m, __shfl_xor(m, 2));
            m = fmaxf(m, __shfl_xor(m, 4));
            m = fmaxf(m, __shfl_xor(m, 8));
            float p = expf(sim - m);
            float s = p;
            s += __shfl_xor(s, 2);
            s += __shfl_xor(s, 4);
            s += __shfl_xor(s, 8);
            float av = p / s;
            if (hf == 0) assign_out[((size_t)(b * N_ + n0 + sn)) * 8 + sk] = av;
            asg[sn * 8 + sk] = av;
        }
        __syncthreads();
        if (t < 8) {
#pragma unroll
            for (int nn = 0; nn < 16; ++nn) massr += asg[nn * 8 + t];
        }
#pragma unroll 4
        for (int nn = 0; nn < 16; ++nn) {
            float4 a03 = *(const float4*)(&asg[nn * 8]);
            float4 a47 = *(const float4*)(&asg[nn * 8 + 4]);
            float fv = ft[nn * 260 + t];
            macc[0] += a03.x * fv; macc[1] += a03.y * fv;
            macc[2] += a03.z * fv; macc[3] += a03.w * fv;
            macc[4] += a47.x * fv; macc[5] += a47.y * fv;
            macc[6] += a47.z * fv; macc[7] += a47.w * fv;
        }
    }
#pragma unroll
    for (int k = 0; k < 8; ++k)
        atomicAdd(&macc_ws[((size_t)(b * 8 + k)) * 256 + t], macc[k]);
    if (t < 8) atomicAdd(&mass_ws[b * 8 + t], massr);
}

// K5: mass-divide + refine residual MLP + salience. grid 256.
__global__ __launch_bounds__(256) void k5_refine(
    const float* __restrict__ macc_ws, const float* __restrict__ mass_ws,
    const float* __restrict__ ref_ln_g, const float* __restrict__ ref_ln_b,
    const float* __restrict__ ref_w1, const float* __restrict__ ref_b1,
    const float* __restrict__ ref_w2, const float* __restrict__ ref_b2,
    const float* __restrict__ sal_w1, const float* __restrict__ sal_b1,
    const float* __restrict__ sal_w2, const float* __restrict__ sal_b2,
    float* __restrict__ part_out, float* __restrict__ sal_out)
{
    __shared__ float raw[8 * 256];
    __shared__ float rn[8 * 256];
    __shared__ float h1[8 * 512];
    __shared__ float pf[8 * 256];
    __shared__ float s1[8 * 64];
    __shared__ float mu[8], rs[8];
    const int t = threadIdx.x, b = blockIdx.x;
    const int wave = t >> 6, lane = t & 63;
#pragma unroll
    for (int r = 0; r < 8; ++r) {
        float mm = fmaxf(mass_ws[b * 8 + r], 1e-6f);
        raw[r * 256 + t] = macc_ws[((size_t)(b * 8 + r)) * 256 + t] / mm;
    }
    __syncthreads();
#pragma unroll
    for (int rr = 0; rr < 2; ++rr) {
        int r = wave + rr * 4;
        float4 v = *(const float4*)(&raw[r * 256 + lane * 4]);
        float s = v.x + v.y + v.z + v.w;
        float s2 = v.x * v.x + v.y * v.y + v.z * v.z + v.w * v.w;
#pragma unroll
        for (int m = 1; m < 64; m <<= 1) { s += __shfl_xor(s, m); s2 += __shfl_xor(s2, m); }
        if (lane == 0) {
            float mean = s * (1.f / 256.f);
            float var = s2 * (1.f / 256.f) - mean * mean;
            mu[r] = mean;
            rs[r] = rsqrtf(var + 1e-5f);
        }
    }
    __syncthreads();
    {
        float gg = ref_ln_g[t], bbv = ref_ln_b[t];
#pragma unroll
        for (int r = 0; r < 8; ++r) {
            float x = raw[r * 256 + t];
            rn[r * 256 + t] = (x - mu[r]) * rs[r] * gg + bbv;
        }
    }
    __syncthreads();
    {
        float acca[8], accb[8];
#pragma unroll
        for (int r = 0; r < 8; ++r) { acca[r] = 0.f; accb[r] = 0.f; }
        for (int d = 0; d < 256; d += 4) {
            float4 rv[8];
#pragma unroll
            for (int r = 0; r < 8; ++r) rv[r] = *(const float4*)(&rn[r * 256 + d]);
            float wa0 = ref_w1[(size_t)(d + 0) * 512 + t], wb0 = ref_w1[(size_t)(d + 0) * 512 + t + 256];
            float wa1 = ref_w1[(size_t)(d + 1) * 512 + t], wb1 = ref_w1[(size_t)(d + 1) * 512 + t + 256];
            float wa2 = ref_w1[(size_t)(d + 2) * 512 + t], wb2 = ref_w1[(size_t)(d + 2) * 512 + t + 256];
            float wa3 = ref_w1[(size_t)(d + 3) * 512 + t], wb3 = ref_w1[(size_t)(d + 3) * 512 + t + 256];
#pragma unroll
            for (int r = 0; r < 8; ++r) {
                acca[r] += rv[r].x * wa0 + rv[r].y * wa1 + rv[r].z * wa2 + rv[r].w * wa3;
                accb[r] += rv[r].x * wb0 + rv[r].y * wb1 + rv[r].z * wb2 + rv[r].w * wb3;
            }
        }
        float b1a = ref_b1[t], b1b = ref_b1[t + 256];
#pragma unroll
        for (int r = 0; r < 8; ++r) {
            h1[r * 512 + t] = gelu_exact(acca[r] + b1a);
            h1[r * 512 + t + 256] = gelu_exact(accb[r] + b1b);
        }
    }
    __syncthreads();
    {
        float acc2[8];
#pragma unroll
        for (int r = 0; r < 8; ++r) acc2[r] = 0.f;
        for (int d = 0; d < 512; d += 4) {
            float4 hv[8];
#pragma unroll
            for (int r = 0; r < 8; ++r) hv[r] = *(const float4*)(&h1[r * 512 + d]);
            float w0 = ref_w2[(size_t)(d + 0) * 256 + t];
            float w1v = ref_w2[(size_t)(d + 1) * 256 + t];
            float w2v = ref_w2[(size_t)(d + 2) * 256 + t];
            float w3v = ref_w2[(size_t)(d + 3) * 256 + t];
#pragma unroll
            for (int r = 0; r < 8; ++r)
                acc2[r] += hv[r].x * w0 + hv[r].y * w1v + hv[r].z * w2v + hv[r].w * w3v;
        }
        float b2v = ref_b2[t];
#pragma unroll
        for (int r = 0; r < 8; ++r) {
            float v = raw[r * 256 + t] + acc2[r] + b2v;
            part_out[((size_t)(b * 8 + r)) * 256 + t] = v;
            pf[r * 256 + t] = v;
        }
    }
    __syncthreads();
    for (int o = t; o < 512; o += 256) {
        int r = o >> 6, j = o & 63;
        float a = 0.f;
        for (int d = 0; d < 256; d += 4) {
            float4 v = *(const float4*)(&pf[r * 256 + d]);
            a += v.x * sal_w1[(d + 0) * 64 + j] + v.y * sal_w1[(d + 1) * 64 + j]
               + v.z * sal_w1[(d + 2) * 64 + j] + v.w * sal_w1[(d + 3) * 64 + j];
        }
        s1[o] = gelu_exact(a + sal_b1[j]);
    }
    __syncthreads();
    if (t < 8) {
        float a = 0.f;
#pragma unroll 8
        for (int d = 0; d < 64; ++d) a += s1[t * 64 + d] * sal_w2[d];
        float x = a + sal_b2[0];
        sal_out[b * 8 + t] = 1.f / (1.f + expf(-x));
    }
}

extern "C" void kernel_launch(void* const* d_in, const int* in_sizes, int n_in,
                              void* d_out, int out_size, void* d_ws, size_t ws_size,
                              hipStream_t stream) {
    const float* patch    = (const float*)d_in[0];
    const int*   alt_idx  = (const int*)d_in[1];
    const int*   epoch    = (const int*)d_in[2];
    const float* w_proj   = (const float*)d_in[3];
    const float* b_proj   = (const float*)d_in[4];
    const float* ln1_g    = (const float*)d_in[5];
    const float* ln1_b    = (const float*)d_in[6];
    const float* protos   = (const float*)d_in[7];
    const float* r_alt    = (const float*)d_in[8];
    const float* r_wf     = (const float*)d_in[9];
    const float* r_bf     = (const float*)d_in[10];
    const float* r_w1     = (const float*)d_in[11];
    const float* r_b1     = (const float*)d_in[12];
    const float* r_w2     = (const float*)d_in[13];
    const float* r_b2     = (const float*)d_in[14];
    const float* ref_ln_g = (const float*)d_in[15];
    const float* ref_ln_b = (const float*)d_in[16];
    const float* ref_w1   = (const float*)d_in[17];
    const float* ref_b1   = (const float*)d_in[18];
    const float* ref_w2   = (const float*)d_in[19];
    const float* ref_b2   = (const float*)d_in[20];
    const float* sal_w1   = (const float*)d_in[21];
    const float* sal_b1   = (const float*)d_in[22];
    const float* sal_w2   = (const float*)d_in[23];
    const float* sal_b2   = (const float*)d_in[24];

    float* out = (float*)d_out;
    float* wsf = (float*)d_ws;
    float* stats   = wsf + WS_STATS;
    float* macc    = wsf + WS_MACC;
    float* mass    = wsf + WS_MASS;
    float* proto_n = wsf + WS_PROTON;
    float* invn    = wsf + WS_INVN;
    unsigned short* btw = (unsigned short*)(wsf + WS_BTW);

    k0_zero<<<dim3((65536 + 524288 + 2048 + 255) / 256), dim3(256), 0, stream>>>(stats, 65536 + 524288 + 2048);
    kB_conv<<<dim3(256), dim3(384), 0, stream>>>(w_proj, btw);
    k1_occ<<<dim3(2304), dim3(256), 0, stream>>>(patch, btw, b_proj, ln1_g, ln1_b,
                                                 out + OFF_FEAT, stats, invn);
    k3_router<<<dim3(256), dim3(256), 0, stream>>>(stats, alt_idx, epoch, r_alt, r_wf, r_bf,
                                                   r_w1, r_b1, r_w2, r_b2, protos,
                                                   out + OFF_GATE, proto_n);
    k4_part<<<dim3(4, 256), dim3(256), 0, stream>>>(out + OFF_FEAT, proto_n, invn,
                                                    out + OFF_ASSIGN, macc, mass);
    k5_refine<<<dim3(256), dim3(256), 0, stream>>>(macc, mass,
                                                   ref_ln_g, ref_ln_b, ref_w1, ref_b1,
                                                   ref_w2, ref_b2, sal_w1, sal_b1, sal_w2, sal_b2,
                                                   out + OFF_PART, out + OFF_SAL);
}

// Round 16
// 284.938 us; speedup vs baseline: 1.3965x; 1.3965x over previous
//
#include <hip/hip_runtime.h>
#include <hip/hip_bf16.h>
#include <math.h>

#define B_ 256
#define N_ 576
#define F_ 384
#define D_ 256
#define K_ 8

// output offsets (floats)
#define OFF_PART   0
#define OFF_ASSIGN 524288
#define OFF_SAL    1703936
#define OFF_FEAT   1705984
#define OFF_GATE   39454720

// workspace layout (floats)
#define WS_STATS   0
#define WS_MACC    65536
#define WS_MASS    589824
#define WS_PROTON  591872
#define WS_INVN    1116160
#define WS_BTW     1263616

#define ZERO_N     591872   // stats + macc + mass (contiguous)

using s16x8 = __attribute__((ext_vector_type(8))) short;
using f32x4 = __attribute__((ext_vector_type(4))) float;

__device__ __forceinline__ float gelu_exact(float x) {
    return 0.5f * x * (1.0f + erff(x * 0.70710678118654752f));
}

__device__ __forceinline__ unsigned short f2b(float f) {
    __hip_bfloat16 h = __float2bfloat16(f);
    unsigned short u;
    __builtin_memcpy(&u, &h, 2);
    return u;
}

// merged init: blocks [0, 2312) zero ws region; blocks [2312, 2696) build Bt.
__global__ __launch_bounds__(256) void kz_init(
    float* __restrict__ zp, const float* __restrict__ w,
    unsigned short* __restrict__ bt)
{
    const int bid = blockIdx.x;
    if (bid < 2312) {
        int i = bid * 256 + threadIdx.x;
        if (i < ZERO_N) zp[i] = 0.f;
    } else {
        int i = (bid - 2312) * 256 + threadIdx.x;   // < 98304
        int n = i / 384, k = i - n * 384;
        bt[i] = f2b(w[k * 256 + n]);
    }
}

// K1 (r13 verified best): chunked GEMM, swapped MFMA operands ->
// acc[m][n][r] = C[row = m*16 + l15][col = w*64 + n*16 + l4*4 + r]; float4 stores.
__global__ __launch_bounds__(256, 3) void k1_swp(
    const float* __restrict__ patch, const unsigned short* __restrict__ btw,
    const float* __restrict__ bias, const float* __restrict__ g,
    const float* __restrict__ bb, float* __restrict__ feat,
    float* __restrict__ stats, float* __restrict__ invn)
{
    __shared__ __align__(16) unsigned short As[64 * 72];   //  9.2 KB
    __shared__ __align__(16) unsigned short Bs[256 * 72];  // 36.9 KB
    __shared__ float rsum[4][64];
    __shared__ float rsq[4][64];
    __shared__ float muS[64], rsS[64];

    const int t = threadIdx.x;
    const int w = t >> 6;
    const int lane = t & 63;
    const int l15 = lane & 15;
    const int l4 = lane >> 4;
    const size_t rowbase = (size_t)blockIdx.x * 64;
    const int bidx = blockIdx.x / 9;   // 9 blocks per batch (9*64 = 576)

    f32x4 acc[4][4];
#pragma unroll
    for (int m = 0; m < 4; ++m)
#pragma unroll
        for (int n = 0; n < 4; ++n)
            acc[m][n] = (f32x4){0.f, 0.f, 0.f, 0.f};

    const int ar = t >> 2;          // A-stage row 0..63
    const int ak = (t & 3) * 16;    // A-stage k offset (16 f32 per thread)
    const int brr = t >> 3;         // B-stage row base 0..31
    const int bk = (t & 7) * 8;     // B-stage k offset (8 bf16 = 16B)

    const float* aptr = patch + (rowbase + ar) * F_ + ak;
    const unsigned short* bptr = btw + (size_t)brr * F_ + bk;

    float4 pa[4];
    s16x8 pb[8];

    // prologue: load chunk 0 into registers
#pragma unroll
    for (int i = 0; i < 4; ++i) pa[i] = *(const float4*)(aptr + 4 * i);
#pragma unroll
    for (int p = 0; p < 8; ++p) pb[p] = *(const s16x8*)(bptr + (size_t)(32 * p) * F_);

    for (int c = 0; c < 6; ++c) {
        __syncthreads();   // previous compute done reading LDS
        {
            s16x8 c0, c1;
            c0[0] = (short)f2b(pa[0].x); c0[1] = (short)f2b(pa[0].y);
            c0[2] = (short)f2b(pa[0].z); c0[3] = (short)f2b(pa[0].w);
            c0[4] = (short)f2b(pa[1].x); c0[5] = (short)f2b(pa[1].y);
            c0[6] = (short)f2b(pa[1].z); c0[7] = (short)f2b(pa[1].w);
            c1[0] = (short)f2b(pa[2].x); c1[1] = (short)f2b(pa[2].y);
            c1[2] = (short)f2b(pa[2].z); c1[3] = (short)f2b(pa[2].w);
            c1[4] = (short)f2b(pa[3].x); c1[5] = (short)f2b(pa[3].y);
            c1[6] = (short)f2b(pa[3].z); c1[7] = (short)f2b(pa[3].w);
            *(s16x8*)&As[ar * 72 + ak] = c0;
            *(s16x8*)&As[ar * 72 + ak + 8] = c1;
#pragma unroll
            for (int p = 0; p < 8; ++p)
                *(s16x8*)&Bs[(brr + 32 * p) * 72 + bk] = pb[p];
        }
        __syncthreads();
        if (c < 5) {
            const int k1 = (c + 1) * 64;
#pragma unroll
            for (int i = 0; i < 4; ++i) pa[i] = *(const float4*)(aptr + k1 + 4 * i);
#pragma unroll
            for (int p = 0; p < 8; ++p) pb[p] = *(const s16x8*)(bptr + (size_t)(32 * p) * F_ + k1);
        }
#pragma unroll
        for (int kk = 0; kk < 2; ++kk) {
            const int kb = kk * 32 + l4 * 8;
            s16x8 afr[4], bfr[4];
#pragma unroll
            for (int m = 0; m < 4; ++m)
                afr[m] = *(const s16x8*)&As[(m * 16 + l15) * 72 + kb];
#pragma unroll
            for (int n = 0; n < 4; ++n)
                bfr[n] = *(const s16x8*)&Bs[(w * 64 + n * 16 + l15) * 72 + kb];
#pragma unroll
            for (int m = 0; m < 4; ++m)
#pragma unroll
                for (int n = 0; n < 4; ++n)
                    acc[m][n] = __builtin_amdgcn_mfma_f32_16x16x32_bf16(bfr[n], afr[m], acc[m][n], 0, 0, 0);
        }
    }

    // ---- swapped-layout epilogue (r13 verified) ----
    float4 bias4[4], g4[4], bb4[4];
#pragma unroll
    for (int n = 0; n < 4; ++n) {
        const int cb = w * 64 + n * 16 + l4 * 4;
        bias4[n] = *(const float4*)&bias[cb];
        g4[n]    = *(const float4*)&g[cb];
        bb4[n]   = *(const float4*)&bb[cb];
    }
#pragma unroll
    for (int m = 0; m < 4; ++m)
#pragma unroll
        for (int n = 0; n < 4; ++n) {
            acc[m][n][0] += bias4[n].x;
            acc[m][n][1] += bias4[n].y;
            acc[m][n][2] += bias4[n].z;
            acc[m][n][3] += bias4[n].w;
        }

    float ps[4], pq[4];
#pragma unroll
    for (int m = 0; m < 4; ++m) {
        float s = 0.f, s2 = 0.f;
#pragma unroll
        for (int n = 0; n < 4; ++n)
#pragma unroll
            for (int r = 0; r < 4; ++r) {
                float x = acc[m][n][r];
                s += x; s2 += x * x;
            }
        s += __shfl_xor(s, 16);  s += __shfl_xor(s, 32);
        s2 += __shfl_xor(s2, 16); s2 += __shfl_xor(s2, 32);
        ps[m] = s; pq[m] = s2;
    }
    if (l4 == 0) {
#pragma unroll
        for (int m = 0; m < 4; ++m) {
            rsum[w][m * 16 + l15] = ps[m];
            rsq[w][m * 16 + l15] = pq[m];
        }
    }
    __syncthreads();
    if (t < 64) {
        float s = rsum[0][t] + rsum[1][t] + rsum[2][t] + rsum[3][t];
        float q = rsq[0][t] + rsq[1][t] + rsq[2][t] + rsq[3][t];
        float mean = s * (1.f / 256.f);
        float var = q * (1.f / 256.f) - mean * mean;
        muS[t] = mean;
        rsS[t] = rsqrtf(var + 1e-5f);
    }
    __syncthreads();

    float cst[4][4];
#pragma unroll
    for (int n = 0; n < 4; ++n)
#pragma unroll
        for (int r = 0; r < 4; ++r) cst[n][r] = 0.f;

#pragma unroll
    for (int m = 0; m < 4; ++m) {
        const int row = m * 16 + l15;
        const float mu = muS[row], ri = rsS[row];
        float qs = 0.f;
        float* fp = feat + (rowbase + row) * 256 + w * 64 + l4 * 4;
#pragma unroll
        for (int n = 0; n < 4; ++n) {
            float z0 = gelu_exact((acc[m][n][0] - mu) * ri * g4[n].x + bb4[n].x);
            float z1 = gelu_exact((acc[m][n][1] - mu) * ri * g4[n].y + bb4[n].y);
            float z2 = gelu_exact((acc[m][n][2] - mu) * ri * g4[n].z + bb4[n].z);
            float z3 = gelu_exact((acc[m][n][3] - mu) * ri * g4[n].w + bb4[n].w);
            float4 zv = {z0, z1, z2, z3};
            *(float4*)(fp + n * 16) = zv;
            cst[n][0] += z0; cst[n][1] += z1; cst[n][2] += z2; cst[n][3] += z3;
            qs += z0 * z0 + z1 * z1 + z2 * z2 + z3 * z3;
        }
        qs += __shfl_xor(qs, 16); qs += __shfl_xor(qs, 32);
        if (l4 == 0) rsq[w][row] = qs;   // reuse rsq: z^2 staging (safe after barrier above)
    }
#pragma unroll
    for (int n = 0; n < 4; ++n)
#pragma unroll
        for (int r = 0; r < 4; ++r) {
            float cv = cst[n][r];
            cv += __shfl_xor(cv, 1); cv += __shfl_xor(cv, 2);
            cv += __shfl_xor(cv, 4); cv += __shfl_xor(cv, 8);
            if (l15 == 0)
                atomicAdd(&stats[bidx * 256 + w * 64 + n * 16 + l4 * 4 + r], cv);
        }
    __syncthreads();
    if (t < 64) {
        float tot = rsq[0][t] + rsq[1][t] + rsq[2][t] + rsq[3][t];
        invn[rowbase + t] = 1.f / fmaxf(sqrtf(tot), 1e-12f);
    }
}

// K3: router + blended-normalized prototypes. grid 256.
__global__ __launch_bounds__(256) void k3_router(
    const float* __restrict__ stats, const int* __restrict__ alt_idx,
    const int* __restrict__ epoch_p,
    const float* __restrict__ r_alt_emb, const float* __restrict__ r_wf,
    const float* __restrict__ r_bf, const float* __restrict__ r_w1,
    const float* __restrict__ r_b1, const float* __restrict__ r_w2,
    const float* __restrict__ r_b2, const float* __restrict__ protos,
    float* __restrict__ gate_out, float* __restrict__ proto_n)
{
    __shared__ float fs[256];
    __shared__ float cv[128];
    __shared__ float hb[64];
    __shared__ float lg[4];
    __shared__ float gate[4];
    __shared__ float pl[8 * 260];
    __shared__ float nrm[8];
    const int t = threadIdx.x, b = blockIdx.x;
    fs[t] = stats[b * D_ + t] * (1.f / (float)N_);
    __syncthreads();
    if (t < 64) {
        float a = 0.f;
        for (int d = 0; d < 256; ++d) a += fs[d] * r_wf[d * 64 + t];
        cv[t] = fmaxf(a + r_bf[t], 0.f);
    } else if (t < 128) {
        int alt = alt_idx[b];
        cv[t] = r_alt_emb[alt * 64 + (t - 64)];
    }
    __syncthreads();
    if (t < 64) {
        float a = 0.f;
        for (int d = 0; d < 128; ++d) a += cv[d] * r_w1[d * 64 + t];
        hb[t] = fmaxf(a + r_b1[t], 0.f);
    }
    __syncthreads();
    if (t < 4) {
        float a = 0.f;
        for (int d = 0; d < 64; ++d) a += hb[d] * r_w2[d * 4 + t];
        int ep = epoch_p[0];
        float warm = fminf((float)ep * (1.f / 8.f), 1.f);
        float temp = 2.f * (1.f - warm) + 0.5f * warm;
        lg[t] = (a + r_b2[t]) / temp;
    }
    __syncthreads();
    if (t == 0) {
        float m = fmaxf(fmaxf(lg[0], lg[1]), fmaxf(lg[2], lg[3]));
        float e0 = expf(lg[0] - m), e1 = expf(lg[1] - m);
        float e2 = expf(lg[2] - m), e3 = expf(lg[3] - m);
        float s = e0 + e1 + e2 + e3;
        gate[0] = e0 / s; gate[1] = e1 / s; gate[2] = e2 / s; gate[3] = e3 / s;
    }
    __syncthreads();
    if (t < 4) gate_out[b * 4 + t] = gate[t];
    float g0 = gate[0], g1 = gate[1], g2 = gate[2], g3 = gate[3];
#pragma unroll
    for (int k = 0; k < 8; ++k) {
        float p = g0 * protos[(0 * 8 + k) * 256 + t] + g1 * protos[(1 * 8 + k) * 256 + t]
                + g2 * protos[(2 * 8 + k) * 256 + t] + g3 * protos[(3 * 8 + k) * 256 + t];
        pl[k * 260 + t] = p;
    }
    __syncthreads();
    const int wave = t >> 6, lane = t & 63;
#pragma unroll
    for (int kk = 0; kk < 2; ++kk) {
        int k = wave * 2 + kk;
        float4 v = *(const float4*)(&pl[k * 260 + lane * 4]);
        float s2 = v.x * v.x + v.y * v.y + v.z * v.z + v.w * v.w;
#pragma unroll
        for (int m = 1; m < 64; m <<= 1) s2 += __shfl_xor(s2, m);
        if (lane == 0) nrm[k] = 1.f / fmaxf(sqrtf(s2), 1e-12f);
    }
    __syncthreads();
#pragma unroll
    for (int k = 0; k < 8; ++k)
        proto_n[((size_t)(b * 8 + k)) * 256 + t] = pl[k * 260 + t] * nrm[k];
}

// K4: sim uses precomputed invn. grid (6,256), 6 tiles each (more blocks: latency overlap).
__global__ __launch_bounds__(256) void k4_part(
    const float* __restrict__ feat, const float* __restrict__ proto_n,
    const float* __restrict__ invn,
    float* __restrict__ assign_out, float* __restrict__ macc_ws,
    float* __restrict__ mass_ws)
{
    __shared__ float pp[8 * 260];
    __shared__ float ft[16 * 260];
    __shared__ float asg[16 * 8];
    __shared__ float inrm[16];
    const int t = threadIdx.x, b = blockIdx.y;
#pragma unroll
    for (int k = 0; k < 8; ++k) pp[k * 260 + t] = proto_n[((size_t)(b * 8 + k)) * 256 + t];
    float macc[8];
#pragma unroll
    for (int k = 0; k < 8; ++k) macc[k] = 0.f;
    float massr = 0.f;
    const int sn = t >> 4;
    const int sk = (t >> 1) & 7;
    const int hf = t & 1;
    const int lc = (t & 15) * 4;
    const int t0 = blockIdx.x * 6;
    for (int tile = t0; tile < t0 + 6; ++tile) {
        int n0 = tile * 16;
        __syncthreads();
        const float* fsrc = feat + ((size_t)(b * N_ + n0 + sn) * D_) + lc;
#pragma unroll
        for (int i = 0; i < 4; ++i) {
            float4 v = *(const float4*)(fsrc + 64 * i);
            *(float4*)(&ft[sn * 260 + lc + 64 * i]) = v;
        }
        if (t < 16) inrm[t] = invn[(size_t)b * N_ + n0 + t];
        __syncthreads();
        {
            const float4* fp = (const float4*)(&ft[sn * 260 + hf * 128]);
            const float4* qp = (const float4*)(&pp[sk * 260 + hf * 128]);
            float a = 0.f;
#pragma unroll 8
            for (int dd = 0; dd < 32; ++dd) {
                float4 fv = fp[dd], qv = qp[dd];
                a += fv.x * qv.x + fv.y * qv.y + fv.z * qv.z + fv.w * qv.w;
            }
            a += __shfl_xor(a, 1);
            float sim = a * inrm[sn] * (1.f / 0.07f);
            float m = sim;
            m = fmaxf(m, __shfl_xor(m, 2));
            m = fmaxf(m, __shfl_xor(m, 4));
            m = fmaxf(m, __shfl_xor(m, 8));
            float p = expf(sim - m);
            float s = p;
            s += __shfl_xor(s, 2);
            s += __shfl_xor(s, 4);
            s += __shfl_xor(s, 8);
            float av = p / s;
            if (hf == 0) assign_out[((size_t)(b * N_ + n0 + sn)) * 8 + sk] = av;
            asg[sn * 8 + sk] = av;
        }
        __syncthreads();
        if (t < 8) {
#pragma unroll
            for (int nn = 0; nn < 16; ++nn) massr += asg[nn * 8 + t];
        }
#pragma unroll 4
        for (int nn = 0; nn < 16; ++nn) {
            float4 a03 = *(const float4*)(&asg[nn * 8]);
            float4 a47 = *(const float4*)(&asg[nn * 8 + 4]);
            float fv = ft[nn * 260 + t];
            macc[0] += a03.x * fv; macc[1] += a03.y * fv;
            macc[2] += a03.z * fv; macc[3] += a03.w * fv;
            macc[4] += a47.x * fv; macc[5] += a47.y * fv;
            macc[6] += a47.z * fv; macc[7] += a47.w * fv;
        }
    }
#pragma unroll
    for (int k = 0; k < 8; ++k)
        atomicAdd(&macc_ws[((size_t)(b * 8 + k)) * 256 + t], macc[k]);
    if (t < 8) atomicAdd(&mass_ws[b * 8 + t], massr);
}

// K5: mass-divide + refine residual MLP + salience. grid 256.
__global__ __launch_bounds__(256) void k5_refine(
    const float* __restrict__ macc_ws, const float* __restrict__ mass_ws,
    const float* __restrict__ ref_ln_g, const float* __restrict__ ref_ln_b,
    const float* __restrict__ ref_w1, const float* __restrict__ ref_b1,
    const float* __restrict__ ref_w2, const float* __restrict__ ref_b2,
    const float* __restrict__ sal_w1, const float* __restrict__ sal_b1,
    const float* __restrict__ sal_w2, const float* __restrict__ sal_b2,
    float* __restrict__ part_out, float* __restrict__ sal_out)
{
    __shared__ float raw[8 * 256];
    __shared__ float rn[8 * 256];
    __shared__ float h1[8 * 512];
    __shared__ float pf[8 * 256];
    __shared__ float s1[8 * 64];
    __shared__ float mu[8], rs[8];
    const int t = threadIdx.x, b = blockIdx.x;
    const int wave = t >> 6, lane = t & 63;
#pragma unroll
    for (int r = 0; r < 8; ++r) {
        float mm = fmaxf(mass_ws[b * 8 + r], 1e-6f);
        raw[r * 256 + t] = macc_ws[((size_t)(b * 8 + r)) * 256 + t] / mm;
    }
    __syncthreads();
#pragma unroll
    for (int rr = 0; rr < 2; ++rr) {
        int r = wave + rr * 4;
        float4 v = *(const float4*)(&raw[r * 256 + lane * 4]);
        float s = v.x + v.y + v.z + v.w;
        float s2 = v.x * v.x + v.y * v.y + v.z * v.z + v.w * v.w;
#pragma unroll
        for (int m = 1; m < 64; m <<= 1) { s += __shfl_xor(s, m); s2 += __shfl_xor(s2, m); }
        if (lane == 0) {
            float mean = s * (1.f / 256.f);
            float var = s2 * (1.f / 256.f) - mean * mean;
            mu[r] = mean;
            rs[r] = rsqrtf(var + 1e-5f);
        }
    }
    __syncthreads();
    {
        float gg = ref_ln_g[t], bbv = ref_ln_b[t];
#pragma unroll
        for (int r = 0; r < 8; ++r) {
            float x = raw[r * 256 + t];
            rn[r * 256 + t] = (x - mu[r]) * rs[r] * gg + bbv;
        }
    }
    __syncthreads();
    {
        float acca[8], accb[8];
#pragma unroll
        for (int r = 0; r < 8; ++r) { acca[r] = 0.f; accb[r] = 0.f; }
        for (int d = 0; d < 256; d += 4) {
            float4 rv[8];
#pragma unroll
            for (int r = 0; r < 8; ++r) rv[r] = *(const float4*)(&rn[r * 256 + d]);
            float wa0 = ref_w1[(size_t)(d + 0) * 512 + t], wb0 = ref_w1[(size_t)(d + 0) * 512 + t + 256];
            float wa1 = ref_w1[(size_t)(d + 1) * 512 + t], wb1 = ref_w1[(size_t)(d + 1) * 512 + t + 256];
            float wa2 = ref_w1[(size_t)(d + 2) * 512 + t], wb2 = ref_w1[(size_t)(d + 2) * 512 + t + 256];
            float wa3 = ref_w1[(size_t)(d + 3) * 512 + t], wb3 = ref_w1[(size_t)(d + 3) * 512 + t + 256];
#pragma unroll
            for (int r = 0; r < 8; ++r) {
                acca[r] += rv[r].x * wa0 + rv[r].y * wa1 + rv[r].z * wa2 + rv[r].w * wa3;
                accb[r] += rv[r].x * wb0 + rv[r].y * wb1 + rv[r].z * wb2 + rv[r].w * wb3;
            }
        }
        float b1a = ref_b1[t], b1b = ref_b1[t + 256];
#pragma unroll
        for (int r = 0; r < 8; ++r) {
            h1[r * 512 + t] = gelu_exact(acca[r] + b1a);
            h1[r * 512 + t + 256] = gelu_exact(accb[r] + b1b);
        }
    }
    __syncthreads();
    {
        float acc2[8];
#pragma unroll
        for (int r = 0; r < 8; ++r) acc2[r] = 0.f;
        for (int d = 0; d < 512; d += 4) {
            float4 hv[8];
#pragma unroll
            for (int r = 0; r < 8; ++r) hv[r] = *(const float4*)(&h1[r * 512 + d]);
            float w0 = ref_w2[(size_t)(d + 0) * 256 + t];
            float w1v = ref_w2[(size_t)(d + 1) * 256 + t];
            float w2v = ref_w2[(size_t)(d + 2) * 256 + t];
            float w3v = ref_w2[(size_t)(d + 3) * 256 + t];
#pragma unroll
            for (int r = 0; r < 8; ++r)
                acc2[r] += hv[r].x * w0 + hv[r].y * w1v + hv[r].z * w2v + hv[r].w * w3v;
        }
        float b2v = ref_b2[t];
#pragma unroll
        for (int r = 0; r < 8; ++r) {
            float v = raw[r * 256 + t] + acc2[r] + b2v;
            part_out[((size_t)(b * 8 + r)) * 256 + t] = v;
            pf[r * 256 + t] = v;
        }
    }
    __syncthreads();
    for (int o = t; o < 512; o += 256) {
        int r = o >> 6, j = o & 63;
        float a = 0.f;
        for (int d = 0; d < 256; d += 4) {
            float4 v = *(const float4*)(&pf[r * 256 + d]);
            a += v.x * sal_w1[(d + 0) * 64 + j] + v.y * sal_w1[(d + 1) * 64 + j]
               + v.z * sal_w1[(d + 2) * 64 + j] + v.w * sal_w1[(d + 3) * 64 + j];
        }
        s1[o] = gelu_exact(a + sal_b1[j]);
    }
    __syncthreads();
    if (t < 8) {
        float a = 0.f;
#pragma unroll 8
        for (int d = 0; d < 64; ++d) a += s1[t * 64 + d] * sal_w2[d];
        float x = a + sal_b2[0];
        sal_out[b * 8 + t] = 1.f / (1.f + expf(-x));
    }
}

extern "C" void kernel_launch(void* const* d_in, const int* in_sizes, int n_in,
                              void* d_out, int out_size, void* d_ws, size_t ws_size,
                              hipStream_t stream) {
    const float* patch    = (const float*)d_in[0];
    const int*   alt_idx  = (const int*)d_in[1];
    const int*   epoch    = (const int*)d_in[2];
    const float* w_proj   = (const float*)d_in[3];
    const float* b_proj   = (const float*)d_in[4];
    const float* ln1_g    = (const float*)d_in[5];
    const float* ln1_b    = (const float*)d_in[6];
    const float* protos   = (const float*)d_in[7];
    const float* r_alt    = (const float*)d_in[8];
    const float* r_wf     = (const float*)d_in[9];
    const float* r_bf     = (const float*)d_in[10];
    const float* r_w1     = (const float*)d_in[11];
    const float* r_b1     = (const float*)d_in[12];
    const float* r_w2     = (const float*)d_in[13];
    const float* r_b2     = (const float*)d_in[14];
    const float* ref_ln_g = (const float*)d_in[15];
    const float* ref_ln_b = (const float*)d_in[16];
    const float* ref_w1   = (const float*)d_in[17];
    const float* ref_b1   = (const float*)d_in[18];
    const float* ref_w2   = (const float*)d_in[19];
    const float* ref_b2   = (const float*)d_in[20];
    const float* sal_w1   = (const float*)d_in[21];
    const float* sal_b1   = (const float*)d_in[22];
    const float* sal_w2   = (const float*)d_in[23];
    const float* sal_b2   = (const float*)d_in[24];

    float* out = (float*)d_out;
    float* wsf = (float*)d_ws;
    float* stats   = wsf + WS_STATS;
    float* macc    = wsf + WS_MACC;
    float* mass    = wsf + WS_MASS;
    float* proto_n = wsf + WS_PROTON;
    float* invn    = wsf + WS_INVN;
    unsigned short* btw = (unsigned short*)(wsf + WS_BTW);

    kz_init<<<dim3(2696), dim3(256), 0, stream>>>(stats, w_proj, btw);
    k1_swp<<<dim3(2304), dim3(256), 0, stream>>>(patch, btw, b_proj, ln1_g, ln1_b,
                                                 out + OFF_FEAT, stats, invn);
    k3_router<<<dim3(256), dim3(256), 0, stream>>>(stats, alt_idx, epoch, r_alt, r_wf, r_bf,
                                                   r_w1, r_b1, r_w2, r_b2, protos,
                                                   out + OFF_GATE, proto_n);
    k4_part<<<dim3(6, 256), dim3(256), 0, stream>>>(out + OFF_FEAT, proto_n, invn,
                                                    out + OFF_ASSIGN, macc, mass);
    k5_refine<<<dim3(256), dim3(256), 0, stream>>>(macc, mass,
                                                   ref_ln_g, ref_ln_b, ref_w1, ref_b1,
                                                   ref_w2, ref_b2, sal_w1, sal_b1, sal_w2, sal_b2,
                                                   out + OFF_PART, out + OFF_SAL);
}